// Round 15
// baseline (472.489 us; speedup 1.0000x reference)
//
#include <hip/hip_runtime.h>
#include <hip/hip_bf16.h>

// GRUCell fused cell. B=16384, d=1024, 2d=2048.
//   inp  = LN(concat(x,h); g1,b1) * dm
//   gates= inp @ Wg + bg ; r=sig(gates[:, :d]); z=sig(gates[:, d:])
//   inp2 = LN(concat(x, h*r); g2,b2) * dm
//   u    = tanh(inp2 @ Wu + bu)
//   out  = h*z + (1-z)*u
//
// R15: B-operand bypasses LDS. Weights are pre-transposed into FRAG-READY
// layout (wtransB): 16B chunk per lane per (nblk,T,wn,s,n). GEMM loads
// B-frags directly global->VGPR (coalesced dwordx4, L1/L2-hot: 8MB weights
// shared chip-wide; wm=0/1 waves read identical chunks -> L1 dedup).
// LDS now stages A only (16KB/block): per-CU-step LDS traffic 288->144KB
// (562 cyc) < MFMA floor (932 cyc) -> MFMA becomes the critical pipe.
// B-loads issue before the staging-drain barrier; L2 latency hides under
// the A-drain. A-side, swizzle, XCD chunk swizzle, epilogues = R13/R14.
//
// Frag layout (chunk = 16B = 8 bf16, index in 16B units):
//   chunk(nblk,T,wn,s,n,lane) = ((((nblk*32+T)*2+wn)*2+s)*4+n)*64 + lane
//   elem e of chunk = bf16(W[k][col]),  k = T*64+s*32+(lane>>4)*8+e,
//                                       col = nblk*128+wn*64+n*16+(lane&15)
//   (matches mfma_16x16x32 B-frag: col=lane&15, k=(lane>>4)*8+e)
//
// ws layout (bytes):
//   [0,            8388608)  BfG bf16 frag-layout Wg   (8 MB)
//   [8388608,     12582912)  BfU bf16 frag-layout Wu   (4 MB)
//   [12582912,    79691776)  ln  bf16 [16384][2048]
//   [79691776,   113246208)  hr  bf16 [16384][1024]
//   [113246208,  146800640)  zb  bf16 [16384][1024]   (big-ws only)
//   [146800640,  180355072)  hb  bf16 [16384][1024]   (big-ws only)

#define BATCH 16384
#define DDIM  1024
#define TWOD  2048
#define LNEPS 1e-5f

#define GBK 64
#define NTH 256

typedef __bf16 bf16x8 __attribute__((ext_vector_type(8)));
typedef float  f32x4  __attribute__((ext_vector_type(4)));
typedef unsigned short ushort4v __attribute__((ext_vector_type(4)));

__device__ __forceinline__ unsigned short f2bf(float f) {
    unsigned int u = __builtin_bit_cast(unsigned int, f);
    u = (u + 0x7FFFu + ((u >> 16) & 1u)) >> 16;   // round-to-nearest-even
    return (unsigned short)u;
}
__device__ __forceinline__ float bf2f(unsigned short s) {
    unsigned int u = ((unsigned int)s) << 16;
    return __builtin_bit_cast(float, u);
}
__device__ __forceinline__ void gload16(const void* g, void* l) {
    __builtin_amdgcn_global_load_lds((__attribute__((address_space(1))) void*)(g),
                                     (__attribute__((address_space(3))) void*)(l),
                                     16u, 0, 0);
}

// ------------- weight transpose + cast into FRAG-READY layout --------------
// W: [K=2048][N] f32. Block handles T = blockIdx.x (64 k's), 64-col band
// c0 = blockIdx.y*64 (nblk = by>>1, wn = by&1). 512 chunks/block, 2/thread.
__global__ __launch_bounds__(256) void wtransB(const float* __restrict__ W,
                                               unsigned short* __restrict__ Bf,
                                               int N) {
    __shared__ float tile[64][65];
    const int T  = blockIdx.x;
    const int by = blockIdx.y;
    const int c0 = by * 64;
    const int nblk = by >> 1;
    const int wn   = by & 1;
    const int tid  = threadIdx.x;
    // phase 1: coalesced load of W[T*64 .. +63][c0 .. +63]
    const int cc = tid & 63;
    const int kr = tid >> 6;           // 0..3
#pragma unroll
    for (int p = 0; p < 16; ++p) {
        const int kk = p * 4 + kr;
        tile[kk][cc] = W[(size_t)(T * 64 + kk) * N + c0 + cc];
    }
    __syncthreads();
    // phase 2: each thread emits chunks lc = 2*tid, 2*tid+1
#pragma unroll
    for (int j = 0; j < 2; ++j) {
        const int lc   = 2 * tid + j;
        const int s    = lc >> 8;
        const int n    = (lc >> 6) & 3;
        const int lane = lc & 63;
        const int q    = lane >> 4;
        const int r16  = lane & 15;
        const int kl   = s * 32 + q * 8;
        const int cl   = n * 16 + r16;
        bf16x8 pk;
#pragma unroll
        for (int e = 0; e < 8; ++e)
            ((unsigned short*)&pk)[e] = f2bf(tile[kl + e][cl]);
        const size_t chunk = ((size_t)(((nblk * 32 + T) * 2 + wn) * 2 + s) * 4 + n) * 64 + lane;
        *reinterpret_cast<bf16x8*>(Bf + chunk * 8) = pk;
    }
}

// ---------------- fused LayerNorm over concat(x, second) -------------------
template <bool SECOND_BF16>
__global__ __launch_bounds__(256) void ln_kernel(const float* __restrict__ x,
                                                 const void* __restrict__ h2,
                                                 const float* __restrict__ g,
                                                 const float* __restrict__ bt,
                                                 const float* __restrict__ dm,
                                                 unsigned short* __restrict__ out,
                                                 unsigned short* __restrict__ hb_out) {
    const int row  = blockIdx.x;
    const int tid  = threadIdx.x;
    const int lane = tid & 63;
    const int w    = tid >> 6;

    const float4 xl = reinterpret_cast<const float4*>(x + (size_t)row * DDIM)[tid];
    float hv[4];
    if (SECOND_BF16) {
        const ushort4v hl = reinterpret_cast<const ushort4v*>(
            (const unsigned short*)h2 + (size_t)row * DDIM)[tid];
#pragma unroll
        for (int j = 0; j < 4; ++j) hv[j] = bf2f(hl[j]);
    } else {
        const float4 hl = reinterpret_cast<const float4*>(
            (const float*)h2 + (size_t)row * DDIM)[tid];
        hv[0] = hl.x; hv[1] = hl.y; hv[2] = hl.z; hv[3] = hl.w;
    }
    float xv[4] = {xl.x, xl.y, xl.z, xl.w};

    if (!SECOND_BF16 && hb_out) {
        ushort4v hp;
#pragma unroll
        for (int j = 0; j < 4; ++j) hp[j] = f2bf(hv[j]);
        reinterpret_cast<ushort4v*>(hb_out + (size_t)row * DDIM)[tid] = hp;
    }

    float s = 0.f, ss = 0.f;
#pragma unroll
    for (int j = 0; j < 4; ++j) { s += xv[j] + hv[j]; ss += xv[j]*xv[j] + hv[j]*hv[j]; }
#pragma unroll
    for (int o = 32; o; o >>= 1) { s += __shfl_xor(s, o); ss += __shfl_xor(ss, o); }
    __shared__ float red[8];
    if (lane == 0) { red[w] = s; red[4 + w] = ss; }
    __syncthreads();
    s  = red[0] + red[1] + red[2] + red[3];
    ss = red[4] + red[5] + red[6] + red[7];
    const float inv  = 1.0f / (float)TWOD;
    const float mu   = s * inv;
    const float var  = ss * inv - mu * mu;
    const float rstd = rsqrtf(var + LNEPS);

    {
        const float4 gv = reinterpret_cast<const float4*>(g)[tid];
        const float4 bv = reinterpret_cast<const float4*>(bt)[tid];
        const float4 dv = reinterpret_cast<const float4*>(dm)[tid];
        ushort4v pk;
        pk[0] = f2bf(((xv[0] - mu) * rstd * gv.x + bv.x) * dv.x);
        pk[1] = f2bf(((xv[1] - mu) * rstd * gv.y + bv.y) * dv.y);
        pk[2] = f2bf(((xv[2] - mu) * rstd * gv.z + bv.z) * dv.z);
        pk[3] = f2bf(((xv[3] - mu) * rstd * gv.w + bv.w) * dv.w);
        reinterpret_cast<ushort4v*>(out + (size_t)row * TWOD)[tid] = pk;
    }
    {
        const float4 gv = reinterpret_cast<const float4*>(g)[256 + tid];
        const float4 bv = reinterpret_cast<const float4*>(bt)[256 + tid];
        const float4 dv = reinterpret_cast<const float4*>(dm)[256 + tid];
        ushort4v pk;
        pk[0] = f2bf(((hv[0] - mu) * rstd * gv.x + bv.x) * dv.x);
        pk[1] = f2bf(((hv[1] - mu) * rstd * gv.y + bv.y) * dv.y);
        pk[2] = f2bf(((hv[2] - mu) * rstd * gv.z + bv.z) * dv.z);
        pk[3] = f2bf(((hv[3] - mu) * rstd * gv.w + bv.w) * dv.w);
        reinterpret_cast<ushort4v*>(out + (size_t)row * TWOD + DDIM)[tid] = pk;
    }
}

// ------------- 128x128 BK=64 GEMM, A in LDS / B frag-loaded ----------------
// A : [16384][2048] bf16 row-major (staged to LDS, granule-XOR swizzle).
// Bf: frag-ready weights (see header). LDS = As only (16KB).
template <int EPI>
__global__ __launch_bounds__(NTH, 3) void gemmbr(const unsigned short* __restrict__ A,
                                                 const unsigned short* __restrict__ Bf,
                                                 const float* __restrict__ bias,
                                                 const float* __restrict__ h,
                                                 const unsigned short* __restrict__ hb,
                                                 unsigned short* __restrict__ hr,
                                                 unsigned short* __restrict__ zb,
                                                 float* __restrict__ zf,
                                                 float* __restrict__ outp,
                                                 int NYB) {
    __shared__ unsigned short As[8192];   // [128][64] bf16, 16KB
    const int tid  = threadIdx.x;
    const int lane = tid & 63;
    const int w    = tid >> 6;        // 0..3
    const int wm   = w >> 1;          // 0..1 (M-warp)
    const int wn   = w & 1;           // 0..1 (N-warp)
    const int q    = lane >> 4;       // 0..3
    const int r16  = lane & 15;

    // XCD-chunk swizzle (bijective: nwg % 8 == 0), y-fastest decode
    const int nwg = gridDim.x;
    const int cid = (blockIdx.x & 7) * (nwg >> 3) + (blockIdx.x >> 3);
    const size_t m0 = (size_t)(cid / NYB) * 128;
    const int    nblk = cid % NYB;       // 128-col block
    const int    n0 = nblk * 128;

    const unsigned short* Ag = A + m0 * TWOD;

    // A staging: 1024 granules; thread covers rows r0, +32, +64, +96.
    const int r0 = tid >> 3;                         // 0..31
    const int sg = (tid & 7) ^ (r0 & 7);
    const unsigned short* aS0 = Ag + (size_t)r0 * TWOD + sg * 8;
    const unsigned short* aS1 = Ag + (size_t)(r0 + 32) * TWOD + sg * 8;
    const unsigned short* aS2 = Ag + (size_t)(r0 + 64) * TWOD + sg * 8;
    const unsigned short* aS3 = Ag + (size_t)(r0 + 96) * TWOD + sg * 8;
    const unsigned dst = (unsigned)w * 1024u;        // + lane*16 by HW

    // A frag reads: phys granule = (s*4+q) ^ (r16&7); byte = row*128 + pg*16.
    const unsigned arow = (unsigned)((wm * 64 + r16) * 128);   // + i*2048
    const unsigned pg0  = (unsigned)(((0 * 4 + q) ^ (r16 & 7)) * 16);
    const unsigned pg1  = (unsigned)(((1 * 4 + q) ^ (r16 & 7)) * 16);

    // B frag base (element units): X(T) = (nblk*32+T)*2 + wn;
    // frag(s,n) at X*4096 + s*2048 + n*512 + lane*8.
    const unsigned bl = (unsigned)lane * 8u;
    const unsigned bx0 = (unsigned)((nblk * 32) * 2 + wn) * 4096u;

    f32x4 acc[4][4] = {};
    const int NT = TWOD / GBK;   // 32

    for (int T = 0; T < NT; ++T) {
        const int k_ = T * GBK;
        // B frags for this tile: 8 coalesced dwordx4 from L1/L2 (no LDS dep)
        const unsigned bb = bx0 + (unsigned)T * 8192u + bl;
        bf16x8 b0[4], b1[4];
#pragma unroll
        for (int n = 0; n < 4; ++n) {
            b0[n] = *(const bf16x8*)(Bf + bb + (unsigned)n * 512u);
            b1[n] = *(const bf16x8*)(Bf + bb + 2048u + (unsigned)n * 512u);
        }
        // A staging (HBM/L3 -> LDS)
        gload16(aS0 + k_, (char*)As + dst);
        gload16(aS1 + k_, (char*)As + dst + 4096u);
        gload16(aS2 + k_, (char*)As + dst + 8192u);
        gload16(aS3 + k_, (char*)As + dst + 12288u);
        __syncthreads();                 // drains A-stage (B already back)
        {
            bf16x8 af[4];
#pragma unroll
            for (int i = 0; i < 4; ++i)
                af[i] = *(const bf16x8*)((const char*)As + arow + (unsigned)i * 2048u + pg0);
#pragma unroll
            for (int i = 0; i < 4; ++i)
#pragma unroll
                for (int n = 0; n < 4; ++n)
                    acc[i][n] = __builtin_amdgcn_mfma_f32_16x16x32_bf16(af[i], b0[n], acc[i][n], 0, 0, 0);
        }
        {
            bf16x8 af[4];
#pragma unroll
            for (int i = 0; i < 4; ++i)
                af[i] = *(const bf16x8*)((const char*)As + arow + (unsigned)i * 2048u + pg1);
#pragma unroll
            for (int i = 0; i < 4; ++i)
#pragma unroll
                for (int n = 0; n < 4; ++n)
                    acc[i][n] = __builtin_amdgcn_mfma_f32_16x16x32_bf16(af[i], b1[n], acc[i][n], 0, 0, 0);
        }
        __syncthreads();
    }

    // epilogue: D col = lane&15, row = (lane>>4)*4 + reg  [verified m89/m91]
#pragma unroll
    for (int n = 0; n < 4; ++n) {
        const int col = n0 + wn * 64 + n * 16 + r16;
        const float bc = bias[col];
#pragma unroll
        for (int m = 0; m < 4; ++m) {
#pragma unroll
            for (int rg = 0; rg < 4; ++rg) {
                const size_t row = m0 + wm * 64 + m * 16 + q * 4 + rg;
                const float v = acc[m][n][rg] + bc;
                if (EPI == 0) {
                    if (col < DDIM) {
                        const float rr = 1.0f / (1.0f + __expf(-v));
                        const size_t idx = row * DDIM + col;
                        const float hvv = hb ? bf2f(hb[idx]) : h[idx];
                        hr[idx] = f2bf(hvv * rr);
                    } else {
                        const float zz = 1.0f / (1.0f + __expf(-v));
                        const size_t zi = row * DDIM + (col - DDIM);
                        if (zb) zb[zi] = f2bf(zz); else zf[zi] = zz;
                    }
                } else {
                    const float u = tanhf(v);
                    const size_t idx = row * DDIM + col;
                    const float zz = zb ? bf2f(zb[idx]) : zf[idx];
                    const float hv = hb ? bf2f(hb[idx]) : h[idx];
                    outp[idx] = hv * zz + (1.0f - zz) * u;
                }
            }
        }
    }
}

// --------------------------------------------------------------------------
extern "C" void kernel_launch(void* const* d_in, const int* in_sizes, int n_in,
                              void* d_out, int out_size, void* d_ws, size_t ws_size,
                              hipStream_t stream) {
    const float* x  = (const float*)d_in[0];
    const float* h  = (const float*)d_in[1];
    const float* Wg = (const float*)d_in[2];
    const float* bg = (const float*)d_in[3];
    const float* Wu = (const float*)d_in[4];
    const float* bu = (const float*)d_in[5];
    const float* g1 = (const float*)d_in[6];
    const float* b1 = (const float*)d_in[7];
    const float* g2 = (const float*)d_in[8];
    const float* b2 = (const float*)d_in[9];
    const float* dm = (const float*)d_in[10];
    float* out = (float*)d_out;

    char* ws = (char*)d_ws;
    unsigned short* BfG = (unsigned short*)(ws);                    // 8 MB
    unsigned short* BfU = (unsigned short*)(ws + 8388608);          // 4 MB
    unsigned short* ln  = (unsigned short*)(ws + 12582912);         // 64 MB
    unsigned short* hr  = (unsigned short*)(ws + 79691776);         // 32 MB
    const bool big = (ws_size >= 180355072ull);
    unsigned short* zb = big ? (unsigned short*)(ws + 113246208) : nullptr;
    unsigned short* hb = big ? (unsigned short*)(ws + 146800640) : nullptr;

    wtransB<<<dim3(32, 32), 256, 0, stream>>>(Wg, BfG, TWOD);
    wtransB<<<dim3(32, 16), 256, 0, stream>>>(Wu, BfU, DDIM);
    ln_kernel<false><<<BATCH, 256, 0, stream>>>(x, (const void*)h, g1, b1, dm, ln, hb);
    // GEMM1: 128 M x 16 N = 2048 blocks (div 8 ok)
    gemmbr<0><<<2048, NTH, 0, stream>>>(ln, BfG, bg, h, hb, hr, zb, out, nullptr, 16);
    ln_kernel<true><<<BATCH, 256, 0, stream>>>(x, (const void*)hr, g2, b2, dm, ln, nullptr);
    // GEMM2: 128 M x 8 N = 1024 blocks (div 8 ok)
    gemmbr<1><<<1024, NTH, 0, stream>>>(ln, BfU, bu, h, hb, nullptr, zb, out, out, 8);
}

// Round 16
// 381.351 us; speedup vs baseline: 1.2390x; 1.2390x over previous
//
#include <hip/hip_runtime.h>
#include <hip/hip_bf16.h>

// GRUCell fused cell. B=16384, d=1024, 2d=2048.
//   inp  = LN(concat(x,h); g1,b1) * dm
//   gates= inp @ Wg + bg ; r=sig(gates[:, :d]); z=sig(gates[:, d:])
//   inp2 = LN(concat(x, h*r); g2,b2) * dm
//   u    = tanh(inp2 @ Wu + bu)
//   out  = h*z + (1-z)*u
//
// R16 = R14 restored (best measured: 380.2 us). R15's B-bypass-LDS
// experiment regressed (GEMM1 205->240 us, MfmaUtil 30->11.5%): per-K-step
// global B-frag loads serialize with the A-stage drain on the VMEM pipe,
// and losing LDS's broadcast amortization cost more than the LDS-traffic
// saving. Reverted.
// Final config: BK=64 m97-structure GEMM (single 32KB LDS buffer,
// immediate-drain __syncthreads, granule-XOR swizzle pair - PMC-verified
// 0 bank conflicts, XCD chunk swizzle with y(N)-fastest decode, 4 blk/CU)
// + bf16 traffic trims (hb emitted by LN1; z staged bf16 in ws).
//
// ws layout (bytes):
//   [0,            8388608)  WgT bf16 [2048][2048]
//   [8388608,     12582912)  WuT bf16 [1024][2048]
//   [12582912,    79691776)  ln  bf16 [16384][2048]
//   [79691776,   113246208)  hr  bf16 [16384][1024]
//   [113246208,  146800640)  zb  bf16 [16384][1024]   (big-ws only)
//   [146800640,  180355072)  hb  bf16 [16384][1024]   (big-ws only)

#define BATCH 16384
#define DDIM  1024
#define TWOD  2048
#define LNEPS 1e-5f

#define GBK 64
#define NTH 256

typedef __bf16 bf16x8 __attribute__((ext_vector_type(8)));
typedef float  f32x4  __attribute__((ext_vector_type(4)));
typedef unsigned short ushort4v __attribute__((ext_vector_type(4)));

__device__ __forceinline__ unsigned short f2bf(float f) {
    unsigned int u = __builtin_bit_cast(unsigned int, f);
    u = (u + 0x7FFFu + ((u >> 16) & 1u)) >> 16;   // round-to-nearest-even
    return (unsigned short)u;
}
__device__ __forceinline__ float bf2f(unsigned short s) {
    unsigned int u = ((unsigned int)s) << 16;
    return __builtin_bit_cast(float, u);
}
__device__ __forceinline__ void gload16(const void* g, void* l) {
    __builtin_amdgcn_global_load_lds((__attribute__((address_space(1))) void*)(g),
                                     (__attribute__((address_space(3))) void*)(l),
                                     16u, 0, 0);
}

// ---------------- weight transpose + f32->bf16 cast ------------------------
__global__ __launch_bounds__(256) void wtrans(const float* __restrict__ W,
                                              unsigned short* __restrict__ WT,
                                              int K, int N) {
    __shared__ float tile[32][33];
    const int k0 = blockIdx.x * 32;
    const int n0 = blockIdx.y * 32;
    const int tx = threadIdx.x & 31;
    const int ty = threadIdx.x >> 5;
#pragma unroll
    for (int p = 0; p < 32; p += 8)
        tile[p + ty][tx] = W[(size_t)(k0 + p + ty) * N + n0 + tx];
    __syncthreads();
#pragma unroll
    for (int p = 0; p < 32; p += 8)
        WT[(size_t)(n0 + p + ty) * K + k0 + tx] = f2bf(tile[tx][p + ty]);
}

// ---------------- fused LayerNorm over concat(x, second) -------------------
// hb_out != null (LN1 big-ws mode): also emit the h-half as bf16.
template <bool SECOND_BF16>
__global__ __launch_bounds__(256) void ln_kernel(const float* __restrict__ x,
                                                 const void* __restrict__ h2,
                                                 const float* __restrict__ g,
                                                 const float* __restrict__ bt,
                                                 const float* __restrict__ dm,
                                                 unsigned short* __restrict__ out,
                                                 unsigned short* __restrict__ hb_out) {
    const int row  = blockIdx.x;
    const int tid  = threadIdx.x;
    const int lane = tid & 63;
    const int w    = tid >> 6;

    const float4 xl = reinterpret_cast<const float4*>(x + (size_t)row * DDIM)[tid];
    float hv[4];
    if (SECOND_BF16) {
        const ushort4v hl = reinterpret_cast<const ushort4v*>(
            (const unsigned short*)h2 + (size_t)row * DDIM)[tid];
#pragma unroll
        for (int j = 0; j < 4; ++j) hv[j] = bf2f(hl[j]);
    } else {
        const float4 hl = reinterpret_cast<const float4*>(
            (const float*)h2 + (size_t)row * DDIM)[tid];
        hv[0] = hl.x; hv[1] = hl.y; hv[2] = hl.z; hv[3] = hl.w;
    }
    float xv[4] = {xl.x, xl.y, xl.z, xl.w};

    if (!SECOND_BF16 && hb_out) {
        ushort4v hp;
#pragma unroll
        for (int j = 0; j < 4; ++j) hp[j] = f2bf(hv[j]);
        reinterpret_cast<ushort4v*>(hb_out + (size_t)row * DDIM)[tid] = hp;
    }

    float s = 0.f, ss = 0.f;
#pragma unroll
    for (int j = 0; j < 4; ++j) { s += xv[j] + hv[j]; ss += xv[j]*xv[j] + hv[j]*hv[j]; }
#pragma unroll
    for (int o = 32; o; o >>= 1) { s += __shfl_xor(s, o); ss += __shfl_xor(ss, o); }
    __shared__ float red[8];
    if (lane == 0) { red[w] = s; red[4 + w] = ss; }
    __syncthreads();
    s  = red[0] + red[1] + red[2] + red[3];
    ss = red[4] + red[5] + red[6] + red[7];
    const float inv  = 1.0f / (float)TWOD;
    const float mu   = s * inv;
    const float var  = ss * inv - mu * mu;
    const float rstd = rsqrtf(var + LNEPS);

    {
        const float4 gv = reinterpret_cast<const float4*>(g)[tid];
        const float4 bv = reinterpret_cast<const float4*>(bt)[tid];
        const float4 dv = reinterpret_cast<const float4*>(dm)[tid];
        ushort4v pk;
        pk[0] = f2bf(((xv[0] - mu) * rstd * gv.x + bv.x) * dv.x);
        pk[1] = f2bf(((xv[1] - mu) * rstd * gv.y + bv.y) * dv.y);
        pk[2] = f2bf(((xv[2] - mu) * rstd * gv.z + bv.z) * dv.z);
        pk[3] = f2bf(((xv[3] - mu) * rstd * gv.w + bv.w) * dv.w);
        reinterpret_cast<ushort4v*>(out + (size_t)row * TWOD)[tid] = pk;
    }
    {
        const float4 gv = reinterpret_cast<const float4*>(g)[256 + tid];
        const float4 bv = reinterpret_cast<const float4*>(bt)[256 + tid];
        const float4 dv = reinterpret_cast<const float4*>(dm)[256 + tid];
        ushort4v pk;
        pk[0] = f2bf(((hv[0] - mu) * rstd * gv.x + bv.x) * dv.x);
        pk[1] = f2bf(((hv[1] - mu) * rstd * gv.y + bv.y) * dv.y);
        pk[2] = f2bf(((hv[2] - mu) * rstd * gv.z + bv.z) * dv.z);
        pk[3] = f2bf(((hv[3] - mu) * rstd * gv.w + bv.w) * dv.w);
        reinterpret_cast<ushort4v*>(out + (size_t)row * TWOD + DDIM)[tid] = pk;
    }
}

// ---------------- 128x128 BK=64 m97-structure bf16 GEMM --------------------
// A : [16384][2048] bf16 row-major; BT: [N][2048] bf16 row-major.
// LDS: As[128][64] + Bs[128][64] bf16 (16KB each; 32KB). 4 blocks/CU.
// Row = 128B = 8 granules. Swizzle: phys granule = logical ^ (row&7);
// stage SOURCE pre-XORed, dest linear, reads apply same XOR (0 conflicts).
// Grid: 1D XCD-chunk swizzled, y(N)-fastest decode (A-panel L2 locality).
template <int EPI>
__global__ __launch_bounds__(NTH, 4) void gemm97(const unsigned short* __restrict__ A,
                                                 const unsigned short* __restrict__ BT,
                                                 const float* __restrict__ bias,
                                                 const float* __restrict__ h,
                                                 const unsigned short* __restrict__ hb,
                                                 unsigned short* __restrict__ hr,
                                                 unsigned short* __restrict__ zb,
                                                 float* __restrict__ zf,
                                                 float* __restrict__ outp,
                                                 int NYB) {
    __shared__ unsigned short As[8192];   // [128][64] bf16, 16KB
    __shared__ unsigned short Bs[8192];
    const int tid  = threadIdx.x;
    const int lane = tid & 63;
    const int w    = tid >> 6;        // 0..3
    const int wm   = w >> 1;          // 0..1 (M-warp)
    const int wn   = w & 1;           // 0..1 (N-warp)
    const int q    = lane >> 4;       // 0..3 (K-chunk)
    const int r16  = lane & 15;

    // XCD-chunk swizzle (bijective: nwg % 8 == 0), y-fastest decode
    const int nwg = gridDim.x;
    const int cid = (blockIdx.x & 7) * (nwg >> 3) + (blockIdx.x >> 3);
    const size_t m0 = (size_t)(cid / NYB) * 128;
    const int    n0 = (cid % NYB) * 128;

    const unsigned short* Ag = A  + m0 * TWOD;
    const unsigned short* Bg = BT + (size_t)n0 * TWOD;

    // staging: tile = 128 rows x 8 granules = 1024 granules; thread t covers
    // granules t, t+256, t+512, t+768 (rows r0, r0+32, r0+64, r0+96).
    const int r0 = tid >> 3;                         // 0..31
    const int sg = (tid & 7) ^ (r0 & 7);
    const unsigned short* aS0 = Ag + (size_t)r0 * TWOD + sg * 8;
    const unsigned short* aS1 = Ag + (size_t)(r0 + 32) * TWOD + sg * 8;
    const unsigned short* aS2 = Ag + (size_t)(r0 + 64) * TWOD + sg * 8;
    const unsigned short* aS3 = Ag + (size_t)(r0 + 96) * TWOD + sg * 8;
    const unsigned short* bS0 = Bg + (size_t)r0 * TWOD + sg * 8;
    const unsigned short* bS1 = Bg + (size_t)(r0 + 32) * TWOD + sg * 8;
    const unsigned short* bS2 = Bg + (size_t)(r0 + 64) * TWOD + sg * 8;
    const unsigned short* bS3 = Bg + (size_t)(r0 + 96) * TWOD + sg * 8;
    const unsigned dst = (unsigned)w * 1024u;        // + lane*16 by HW

    // frag reads: row = (wm|wn)*64 + i*16 + r16; sub-k s, chunk q ->
    // phys granule = (s*4+q) ^ (r16&7); byte = row*128 + pg*16.
    const unsigned arow = (unsigned)((wm * 64 + r16) * 128);   // + i*2048
    const unsigned brow = (unsigned)((wn * 64 + r16) * 128);   // + n*2048
    const unsigned pg0  = (unsigned)(((0 * 4 + q) ^ (r16 & 7)) * 16);
    const unsigned pg1  = (unsigned)(((1 * 4 + q) ^ (r16 & 7)) * 16);

    f32x4 acc[4][4] = {};
    const int NT = TWOD / GBK;   // 32

    for (int T = 0; T < NT; ++T) {
        const int k_ = T * GBK;
        gload16(aS0 + k_, (char*)As + dst);
        gload16(aS1 + k_, (char*)As + dst + 4096u);
        gload16(aS2 + k_, (char*)As + dst + 8192u);
        gload16(aS3 + k_, (char*)As + dst + 12288u);
        gload16(bS0 + k_, (char*)Bs + dst);
        gload16(bS1 + k_, (char*)Bs + dst + 4096u);
        gload16(bS2 + k_, (char*)Bs + dst + 8192u);
        gload16(bS3 + k_, (char*)Bs + dst + 12288u);
        __syncthreads();                 // full drain (m97 semantics)
        {
            bf16x8 af[4], bfr[4];
#pragma unroll
            for (int n = 0; n < 4; ++n)
                bfr[n] = *(const bf16x8*)((const char*)Bs + brow + (unsigned)n * 2048u + pg0);
#pragma unroll
            for (int i = 0; i < 4; ++i)
                af[i] = *(const bf16x8*)((const char*)As + arow + (unsigned)i * 2048u + pg0);
#pragma unroll
            for (int i = 0; i < 4; ++i)
#pragma unroll
                for (int n = 0; n < 4; ++n)
                    acc[i][n] = __builtin_amdgcn_mfma_f32_16x16x32_bf16(af[i], bfr[n], acc[i][n], 0, 0, 0);
        }
        {
            bf16x8 af[4], bfr[4];
#pragma unroll
            for (int n = 0; n < 4; ++n)
                bfr[n] = *(const bf16x8*)((const char*)Bs + brow + (unsigned)n * 2048u + pg1);
#pragma unroll
            for (int i = 0; i < 4; ++i)
                af[i] = *(const bf16x8*)((const char*)As + arow + (unsigned)i * 2048u + pg1);
#pragma unroll
            for (int i = 0; i < 4; ++i)
#pragma unroll
                for (int n = 0; n < 4; ++n)
                    acc[i][n] = __builtin_amdgcn_mfma_f32_16x16x32_bf16(af[i], bfr[n], acc[i][n], 0, 0, 0);
        }
        __syncthreads();
    }

    // epilogue: D col = lane&15, row = (lane>>4)*4 + reg  [verified m89/m91]
#pragma unroll
    for (int n = 0; n < 4; ++n) {
        const int col = n0 + wn * 64 + n * 16 + r16;
        const float bc = bias[col];
#pragma unroll
        for (int m = 0; m < 4; ++m) {
#pragma unroll
            for (int rg = 0; rg < 4; ++rg) {
                const size_t row = m0 + wm * 64 + m * 16 + q * 4 + rg;
                const float v = acc[m][n][rg] + bc;
                if (EPI == 0) {
                    if (col < DDIM) {
                        const float rr = 1.0f / (1.0f + __expf(-v));
                        const size_t idx = row * DDIM + col;
                        const float hvv = hb ? bf2f(hb[idx]) : h[idx];
                        hr[idx] = f2bf(hvv * rr);
                    } else {
                        const float zz = 1.0f / (1.0f + __expf(-v));
                        const size_t zi = row * DDIM + (col - DDIM);
                        if (zb) zb[zi] = f2bf(zz); else zf[zi] = zz;
                    }
                } else {
                    const float u = tanhf(v);
                    const size_t idx = row * DDIM + col;
                    const float zz = zb ? bf2f(zb[idx]) : zf[idx];
                    const float hv = hb ? bf2f(hb[idx]) : h[idx];
                    outp[idx] = hv * zz + (1.0f - zz) * u;
                }
            }
        }
    }
}

// --------------------------------------------------------------------------
extern "C" void kernel_launch(void* const* d_in, const int* in_sizes, int n_in,
                              void* d_out, int out_size, void* d_ws, size_t ws_size,
                              hipStream_t stream) {
    const float* x  = (const float*)d_in[0];
    const float* h  = (const float*)d_in[1];
    const float* Wg = (const float*)d_in[2];
    const float* bg = (const float*)d_in[3];
    const float* Wu = (const float*)d_in[4];
    const float* bu = (const float*)d_in[5];
    const float* g1 = (const float*)d_in[6];
    const float* b1 = (const float*)d_in[7];
    const float* g2 = (const float*)d_in[8];
    const float* b2 = (const float*)d_in[9];
    const float* dm = (const float*)d_in[10];
    float* out = (float*)d_out;

    char* ws = (char*)d_ws;
    unsigned short* WgT = (unsigned short*)(ws);                    // 8 MB
    unsigned short* WuT = (unsigned short*)(ws + 8388608);          // 4 MB
    unsigned short* ln  = (unsigned short*)(ws + 12582912);         // 64 MB
    unsigned short* hr  = (unsigned short*)(ws + 79691776);         // 32 MB
    const bool big = (ws_size >= 180355072ull);
    unsigned short* zb = big ? (unsigned short*)(ws + 113246208) : nullptr;
    unsigned short* hb = big ? (unsigned short*)(ws + 146800640) : nullptr;

    wtrans<<<dim3(64, 64), 256, 0, stream>>>(Wg, WgT, TWOD, TWOD);
    wtrans<<<dim3(64, 32), 256, 0, stream>>>(Wu, WuT, TWOD, DDIM);
    ln_kernel<false><<<BATCH, 256, 0, stream>>>(x, (const void*)h, g1, b1, dm, ln, hb);
    // GEMM1: 128 M x 16 N = 2048 blocks (div 8 ok; = 2.0 rounds at 4 blk/CU)
    gemm97<0><<<2048, NTH, 0, stream>>>(ln, WgT, bg, h, hb, hr, zb, out, nullptr, 16);
    ln_kernel<true><<<BATCH, 256, 0, stream>>>(x, (const void*)hr, g2, b2, dm, ln, nullptr);
    // GEMM2: 128 M x 8 N = 1024 blocks (exactly 1 co-resident round)
    gemm97<1><<<1024, NTH, 0, stream>>>(ln, WuT, bu, h, hb, nullptr, zb, out, out, 8);
}